// Round 9
// baseline (173.471 us; speedup 1.0000x reference)
//
#include <hip/hip_runtime.h>
#include <hip/hip_bf16.h>

#define B_ 8
#define N_ 1024
#define F_ 256
#define OUT_ 256
#define REL_ 16
#define NADJ_ 7

typedef __attribute__((ext_vector_type(8))) _Float16 f16x8;
typedef __attribute__((ext_vector_type(4))) _Float16 f16x4;
typedef __attribute__((ext_vector_type(4))) float f32x4;

__device__ __forceinline__ void gll16(const _Float16* g, _Float16* l) {
    __builtin_amdgcn_global_load_lds(
        (const __attribute__((address_space(1))) void*)g,
        (__attribute__((address_space(3))) void*)l, 16, 0, 0);
}

__device__ __forceinline__ f16x8 cvt8(float4 a, float4 b) {
    return f16x8{(_Float16)a.x, (_Float16)a.y, (_Float16)a.z, (_Float16)a.w,
                 (_Float16)b.x, (_Float16)b.y, (_Float16)b.z, (_Float16)b.w};
}

#define MEMPIN() asm volatile("" ::: "memory")

// perm order: rr 0..3 = r{0,1,3,4} (real adjacency), 4..6 = r{2,5,6} (identity adjacency)
__constant__ const int c_perm[7] = {0, 1, 3, 4, 2, 5, 6};

// ---------------- prep: cbias (blocks 0..6) | transW (7..1798) | cvt feat (1799..2822) ---
__global__ __launch_bounds__(256) void prep_kernel(const float* __restrict__ W,
                                                   const float* __restrict__ We,
                                                   const float* __restrict__ feat,
                                                   float* __restrict__ cb,
                                                   _Float16* __restrict__ WTp,
                                                   _Float16* __restrict__ Fe) {
    int bid = blockIdx.x, tid = threadIdx.x;
    if (bid < 7) {
        int idx = bid * 256 + tid;
        int j = idx / OUT_, o = idx % OUT_;
        int r = c_perm[j];
        const float* Wr = W + (size_t)r * (F_ + REL_) * OUT_;
        float s = 0.f;
#pragma unroll
        for (int d = 0; d < REL_; ++d) s += We[r * REL_ + d] * Wr[(F_ + d) * OUT_ + o];
        cb[idx] = s;
    } else if (bid < 1799) {
        int idx = (bid - 7) * 256 + tid;  // 7*65536 total
        int j = idx >> 16, rem = idx & 65535, o = rem >> 8, f = rem & 255;
        int r = c_perm[j];
        WTp[idx] = (_Float16)W[((size_t)r * (F_ + REL_) + f) * OUT_ + o];
    } else {
        int i = (bid - 1799) * 256 + tid;  // 262144 groups of 8
        size_t base = (size_t)i * 8;
        float4 a = *(const float4*)(feat + base);
        float4 b = *(const float4*)(feat + base + 4);
        *(f16x8*)(Fe + base) = cvt8(a, b);
    }
}

// ======= hw7: blocks [0,896): 7 HW GEMMs (3-stage gll16, verified r5-r8).
//         blocks [896,9088): A1/A2 -> f16 copy into Af (bandwidth-bound, overlaps GEMMs).
// z<4: HWT[z][b][o][m_local] = (Fe @ W[z])^T + cb ; z>=4: HWN[z-4][m][o] = Fe @ W[z] + cb.
__global__ __launch_bounds__(256) void hw7_kernel(const float* __restrict__ A1,
                                                  const float* __restrict__ A2,
                                                  const _Float16* __restrict__ Fe,
                                                  const _Float16* __restrict__ WTp,
                                                  const float* __restrict__ cb,
                                                  _Float16* __restrict__ HWT,
                                                  _Float16* __restrict__ HWN,
                                                  _Float16* __restrict__ Af) {
    __shared__ _Float16 S[3 * 8192];  // stage st: As = S+st*8192, Bs = As+4096 (BK=32)
    const int bid = blockIdx.x, tid = threadIdx.x;
    if (bid >= 896) {
        // A -> f16 cvt: 8192 blocks x 2048 elems = 16,777,216 = 2 x 8M
        size_t idx = ((size_t)(bid - 896) * 256 + tid) * 8;
        const float* src = (idx < 8388608) ? (A1 + idx) : (A2 + (idx - 8388608));
        float4 a = *(const float4*)(src);
        float4 b = *(const float4*)(src + 4);
        *(f16x8*)(Af + idx) = cvt8(a, b);
        return;
    }
    const int z = bid / 128, rem = bid % 128, bx = rem & 63, by = rem >> 6;
    const bool tr = (z < 4);
    const _Float16* A  = tr ? (WTp + (size_t)z * 65536) : Fe;
    const _Float16* Bt = tr ? Fe : (WTp + (size_t)z * 65536);
    const int m0 = (tr ? by : bx) * 128;
    const int n0 = (tr ? bx : by) * 128;
    const int wave = tid >> 6, lane = tid & 63, lm = lane & 15, q = lane >> 4;
    const int wr = (wave >> 1) * 64, wc = (wave & 1) * 64;
    const int srow = tid >> 2, sk = (tid & 3) * 8;
    const _Float16* ga0 = A + (size_t)(m0 + srow) * F_ + sk;
    const _Float16* ga1 = ga0 + (size_t)64 * F_;
    const _Float16* gb0 = Bt + (size_t)(n0 + srow) * F_ + sk;
    const _Float16* gb1 = gb0 + (size_t)64 * F_;

    f32x4 acc[4][4] = {};
    const int NT = 8;

    {
        gll16(ga0, S + tid * 8);
        gll16(ga1, S + 2048 + tid * 8);
        gll16(gb0, S + 4096 + tid * 8);
        gll16(gb1, S + 6144 + tid * 8);
        MEMPIN();
        gll16(ga0 + 32, S + 8192 + tid * 8);
        gll16(ga1 + 32, S + 8192 + 2048 + tid * 8);
        gll16(gb0 + 32, S + 8192 + 4096 + tid * 8);
        gll16(gb1 + 32, S + 8192 + 6144 + tid * 8);
        asm volatile("s_waitcnt vmcnt(4)" ::: "memory");  // stage-0 landed (mine)
        __builtin_amdgcn_s_barrier();
    }
    int cs = 0, ns = 1, fs = 2;
    for (int t = 0; t < NT; ++t) {
        if (t + 2 < NT) {
            const int k = (t + 2) * 32;
            _Float16* sb = S + fs * 8192;
            gll16(ga0 + k, sb + tid * 8);
            gll16(ga1 + k, sb + 2048 + tid * 8);
            gll16(gb0 + k, sb + 4096 + tid * 8);
            gll16(gb1 + k, sb + 6144 + tid * 8);
        }
        {
            const _Float16* Au = S + cs * 8192;
            const _Float16* Bu = Au + 4096;
            f16x8 af[4], bf[4];
#pragma unroll
            for (int i = 0; i < 4; ++i) af[i] = *(const f16x8*)(Au + (wr + i * 16 + lm) * 32 + q * 8);
#pragma unroll
            for (int j = 0; j < 4; ++j) bf[j] = *(const f16x8*)(Bu + (wc + j * 16 + lm) * 32 + q * 8);
            __builtin_amdgcn_s_setprio(1);
#pragma unroll
            for (int i = 0; i < 4; ++i)
#pragma unroll
                for (int j = 0; j < 4; ++j)
                    acc[i][j] = __builtin_amdgcn_mfma_f32_16x16x32_f16(af[i], bf[j], acc[i][j], 0, 0, 0);
            __builtin_amdgcn_s_setprio(0);
        }
        if (t + 1 < NT) {
            if (t + 2 < NT) asm volatile("s_waitcnt vmcnt(4)" ::: "memory");
            else            asm volatile("s_waitcnt vmcnt(0)" ::: "memory");
            __builtin_amdgcn_s_barrier();
        }
        int tmp = cs; cs = ns; ns = fs; fs = tmp;
    }
    const float* cbz = cb + (size_t)z * 256;
    if (tr) {
        // HWT[z][b][o][m_local]; tile lies in one b (n0 = bx*128)
        _Float16* C = HWT + (size_t)z * (8 * 256 * 1024) + (size_t)(n0 >> 10) * (256 * 1024);
        const int nl = n0 & 1023;
#pragma unroll
        for (int i = 0; i < 4; ++i)
#pragma unroll
            for (int j = 0; j < 4; ++j)
#pragma unroll
                for (int g = 0; g < 4; ++g) {
                    int row = wr + i * 16 + q * 4 + g;   // o
                    int col = wc + j * 16 + lm;          // m_local
                    float v = acc[i][j][g] + cbz[m0 + row];
                    C[(size_t)(m0 + row) * 1024 + nl + col] = (_Float16)v;
                }
    } else {
        _Float16* C = HWN + (size_t)(z - 4) * ((size_t)8192 * 256);
#pragma unroll
        for (int i = 0; i < 4; ++i)
#pragma unroll
            for (int j = 0; j < 4; ++j)
#pragma unroll
                for (int g = 0; g < 4; ++g) {
                    int row = wr + i * 16 + q * 4 + g;   // m
                    int col = wc + j * 16 + lm;          // o
                    float v = acc[i][j][g] + cbz[n0 + col];
                    C[(size_t)(m0 + row) * 256 + (n0 + col)] = (_Float16)v;
                }
    }
}

// ======= phase2: AHW[kh][rr][b][n][o] partial = A_rr[b][k-half] @ HWT[rr][b]-half^T ====
// f16 A (Af) everywhere. rr<2: ALL-gll16 (A+B), hw7's exact 3-stage counted-vmcnt loop.
// rr>=2: round-5-verified 3-stage reg-staged transpose scatter, f16 source reads.
// BK=32, LDS 48 KB -> 3 blocks/CU. Grid 1024. Mapping: b = d&7 (one b per XCD; A-f16
// footprint/XCD ~6 MB ~ L2), slot = [kh | rr | member | mt].
__global__ __launch_bounds__(256) void p2_kernel(const _Float16* __restrict__ Af,
                                                 const _Float16* __restrict__ HWT,
                                                 _Float16* __restrict__ AHW) {
    __shared__ _Float16 As[3 * 4096];
    __shared__ _Float16 Bs[3 * 4096];
    const int d = blockIdx.x;
    const int b = d & 7, slot = d >> 3;
    const int kh = slot >> 6;                 // K half
    const int rr = (slot >> 4) & 3;           // relation
    const int member = (slot >> 3) & 1;       // o-tile
    const int mt = slot & 7;                  // m-tile

    const size_t slab = (size_t)B_ * N_ * OUT_;
    const _Float16* Ag = Af + (size_t)((rr & 1) * 8 + b) * 1048576;
    const _Float16* Bt = HWT + (size_t)(rr * 8 + b) * (256 * 1024);
    _Float16* C = AHW + (size_t)kh * (4 * slab) + (size_t)rr * slab + (size_t)b * (N_ * OUT_);
    const int m0 = mt * 128, n0 = member * 128, kbase = kh * 512;
    const int tid = threadIdx.x;
    const int wave = tid >> 6, lane = tid & 63, lm = lane & 15, q = lane >> 4;
    const int wr = (wave >> 1) * 64, wc = (wave & 1) * 64;
    const int srow = tid >> 2, sk = (tid & 3) * 8;
    const _Float16* gb0 = Bt + (size_t)(n0 + srow) * 1024 + kbase + sk;
    const _Float16* gb1 = gb0 + (size_t)64 * 1024;

    f32x4 acc[4][4] = {};
    const int NT = 16;

    if (rr < 2) {
        // ---- straight: all-gll16, hw7's exact 3-stage loop (linear LDS) ----
        const _Float16* ga0 = Ag + (size_t)(m0 + srow) * 1024 + kbase + sk;
        const _Float16* ga1 = ga0 + (size_t)64 * 1024;
        auto ST = [&](int st, int k) {
            gll16(ga0 + k, As + st * 4096 + tid * 8);
            gll16(ga1 + k, As + st * 4096 + 2048 + tid * 8);
            gll16(gb0 + k, Bs + st * 4096 + tid * 8);
            gll16(gb1 + k, Bs + st * 4096 + 2048 + tid * 8);
        };
        ST(0, 0);
        MEMPIN();
        ST(1, 32);
        asm volatile("s_waitcnt vmcnt(4)" ::: "memory");  // stage-0 landed (mine)
        __builtin_amdgcn_s_barrier();
        int cs = 0, ns = 1, fs = 2;
        for (int t = 0; t < NT; ++t) {
            if (t + 2 < NT) ST(fs, (t + 2) * 32);
            {
                const _Float16* Au = As + cs * 4096;
                const _Float16* Bu = Bs + cs * 4096;
                f16x8 af[4], bf[4];
#pragma unroll
                for (int i = 0; i < 4; ++i) af[i] = *(const f16x8*)(Au + (wr + i * 16 + lm) * 32 + q * 8);
#pragma unroll
                for (int j = 0; j < 4; ++j) bf[j] = *(const f16x8*)(Bu + (wc + j * 16 + lm) * 32 + q * 8);
                __builtin_amdgcn_s_setprio(1);
#pragma unroll
                for (int i = 0; i < 4; ++i)
#pragma unroll
                    for (int j = 0; j < 4; ++j)
                        acc[i][j] = __builtin_amdgcn_mfma_f32_16x16x32_f16(af[i], bf[j], acc[i][j], 0, 0, 0);
                __builtin_amdgcn_s_setprio(0);
            }
            if (t + 1 < NT) {
                if (t + 2 < NT) asm volatile("s_waitcnt vmcnt(4)" ::: "memory");
                else            asm volatile("s_waitcnt vmcnt(0)" ::: "memory");
                __builtin_amdgcn_s_barrier();
            }
            int tmp = cs; cs = ns; ns = fs; fs = tmp;
        }
    } else {
        // ---- transposed: As[m][k] = Ag[kbase+t*32+kk][m0+m], f16 reads, swizzled scatter
        const int kk4 = (tid >> 5) * 4;          // 0..28
        const int ms4 = (tid & 31) * 4;          // 0..124
        const int tsw = ((ms4 >> 4) & 3) << 3;
        const int wof = ms4 * 32 + (kk4 ^ tsw);
        const _Float16* gA0 = Ag + (size_t)(kbase + kk4) * 1024 + m0 + ms4;
        f16x4 r0, r1, r2, r3;
        {   // prologue
            f16x4 q0 = *(const f16x4*)(gA0);
            f16x4 q1 = *(const f16x4*)(gA0 + 1024);
            f16x4 q2 = *(const f16x4*)(gA0 + 2048);
            f16x4 q3 = *(const f16x4*)(gA0 + 3072);
            _Float16* wp = As + wof;
            *(f16x4*)(wp + 0 * 32) = f16x4{q0[0], q1[0], q2[0], q3[0]};
            *(f16x4*)(wp + 1 * 32) = f16x4{q0[1], q1[1], q2[1], q3[1]};
            *(f16x4*)(wp + 2 * 32) = f16x4{q0[2], q1[2], q2[2], q3[2]};
            *(f16x4*)(wp + 3 * 32) = f16x4{q0[3], q1[3], q2[3], q3[3]};
            MEMPIN();
            gll16(gb0, Bs + tid * 8);
            gll16(gb1, Bs + 2048 + tid * 8);
            MEMPIN();
            const _Float16* p = gA0 + (size_t)32 * 1024;
            r0 = *(const f16x4*)(p);
            r1 = *(const f16x4*)(p + 1024);
            r2 = *(const f16x4*)(p + 2048);
            r3 = *(const f16x4*)(p + 3072);
            MEMPIN();
            gll16(gb0 + 32, Bs + 4096 + tid * 8);
            gll16(gb1 + 32, Bs + 4096 + 2048 + tid * 8);
            asm volatile("s_waitcnt vmcnt(6)" ::: "memory");
            asm volatile("s_waitcnt lgkmcnt(0)" ::: "memory");
            __builtin_amdgcn_s_barrier();
        }
        const _Float16* gp = gA0 + (size_t)64 * 1024;
        int cs = 0, ns = 1, fs = 2;
        for (int t = 0; t < NT; ++t) {
            if (t + 1 < NT) {
                _Float16* wp = As + ns * 4096 + wof;
                *(f16x4*)(wp + 0 * 32) = f16x4{r0[0], r1[0], r2[0], r3[0]};
                *(f16x4*)(wp + 1 * 32) = f16x4{r0[1], r1[1], r2[1], r3[1]};
                *(f16x4*)(wp + 2 * 32) = f16x4{r0[2], r1[2], r2[2], r3[2]};
                *(f16x4*)(wp + 3 * 32) = f16x4{r0[3], r1[3], r2[3], r3[3]};
            }
            MEMPIN();
            if (t + 2 < NT) {
                r0 = *(const f16x4*)(gp);
                r1 = *(const f16x4*)(gp + 1024);
                r2 = *(const f16x4*)(gp + 2048);
                r3 = *(const f16x4*)(gp + 3072);
                gp += (size_t)32 * 1024;
                MEMPIN();
                const int k2 = (t + 2) * 32;
                gll16(gb0 + k2, Bs + fs * 4096 + tid * 8);
                gll16(gb1 + k2, Bs + fs * 4096 + 2048 + tid * 8);
            }
            {
                const _Float16* Au = As + cs * 4096;
                const _Float16* Bu = Bs + cs * 4096;
                f16x8 af[4], bf[4];
#pragma unroll
                for (int i = 0; i < 4; ++i)
                    af[i] = *(const f16x8*)(Au + (wr + i * 16 + lm) * 32 + ((q ^ i) * 8));
#pragma unroll
                for (int j = 0; j < 4; ++j)
                    bf[j] = *(const f16x8*)(Bu + (wc + j * 16 + lm) * 32 + q * 8);
                __builtin_amdgcn_s_setprio(1);
#pragma unroll
                for (int i = 0; i < 4; ++i)
#pragma unroll
                    for (int j = 0; j < 4; ++j)
                        acc[i][j] = __builtin_amdgcn_mfma_f32_16x16x32_f16(af[i], bf[j], acc[i][j], 0, 0, 0);
                __builtin_amdgcn_s_setprio(0);
            }
            if (t + 1 < NT) {
                if (t + 2 < NT) asm volatile("s_waitcnt vmcnt(6)" ::: "memory");
                else            asm volatile("s_waitcnt vmcnt(0)" ::: "memory");
                asm volatile("s_waitcnt lgkmcnt(0)" ::: "memory");
                __builtin_amdgcn_s_barrier();
            }
            int tmp = cs; cs = ns; ns = fs; fs = tmp;
        }
    }
#pragma unroll
    for (int i = 0; i < 4; ++i)
#pragma unroll
        for (int j = 0; j < 4; ++j)
#pragma unroll
            for (int g = 0; g < 4; ++g) {
                int row = wr + i * 16 + q * 4 + g;
                int col = wc + j * 16 + lm;
                C[(size_t)(m0 + row) * 256 + (n0 + col)] = (_Float16)acc[i][j][g];
            }
}

// ======= final: out = max over rr of (AHW_half0 + AHW_half1), max with HWN, + bias =======
__global__ __launch_bounds__(256) void max_kernel(const _Float16* __restrict__ AHW,
                                                  const _Float16* __restrict__ HWN,
                                                  const float* __restrict__ bias,
                                                  float* __restrict__ out) {
    size_t i = ((size_t)blockIdx.x * 256 + threadIdx.x) * 8;
    const size_t slab = (size_t)B_ * N_ * OUT_;
    const size_t HS = 4 * slab;
    float m[8];
    {
        f16x8 v0 = *(const f16x8*)(AHW + i);
        f16x8 v1 = *(const f16x8*)(AHW + HS + i);
#pragma unroll
        for (int e = 0; e < 8; ++e) m[e] = (float)v0[e] + (float)v1[e];
    }
#pragma unroll
    for (int rr = 1; rr < 4; ++rr) {
        f16x8 v0 = *(const f16x8*)(AHW + rr * slab + i);
        f16x8 v1 = *(const f16x8*)(AHW + HS + rr * slab + i);
#pragma unroll
        for (int e = 0; e < 8; ++e) m[e] = fmaxf(m[e], (float)v0[e] + (float)v1[e]);
    }
#pragma unroll
    for (int j = 0; j < 3; ++j) {
        f16x8 w = *(const f16x8*)(HWN + j * slab + i);
#pragma unroll
        for (int e = 0; e < 8; ++e) m[e] = fmaxf(m[e], (float)w[e]);
    }
    size_t bidx = i & ((size_t)N_ * OUT_ - 1);
    float4 b0 = *(const float4*)(bias + bidx);
    float4 b1 = *(const float4*)(bias + bidx + 4);
    float4 o0 = {m[0] + b0.x, m[1] + b0.y, m[2] + b0.z, m[3] + b0.w};
    float4 o1 = {m[4] + b1.x, m[5] + b1.y, m[6] + b1.z, m[7] + b1.w};
    *(float4*)(out + i) = o0;
    *(float4*)(out + i + 4) = o1;
}

// ======================= round-1 fallback path (ws too small) ===========================
__global__ void cbias_kernel(const float* __restrict__ W, const float* __restrict__ We,
                             float* __restrict__ c) {
    int idx = blockIdx.x * 256 + threadIdx.x;
    if (idx >= NADJ_ * OUT_) return;
    int r = idx / OUT_, o = idx % OUT_;
    const float* Wr = W + (size_t)r * (F_ + REL_) * OUT_;
    float s = 0.f;
#pragma unroll
    for (int d = 0; d < REL_; ++d) s += We[r * REL_ + d] * Wr[(F_ + d) * OUT_ + o];
    c[idx] = s;
}

__global__ __launch_bounds__(256) void hw_kernel(const float* __restrict__ feat,
                                                 const float* __restrict__ W,
                                                 const float* __restrict__ cb,
                                                 _Float16* __restrict__ HWb) {
    __shared__ _Float16 As[64][32];
    __shared__ _Float16 Bs[64][32];
    const int mt = blockIdx.x, ct = blockIdx.y;
    const int tid = threadIdx.x, wave = tid >> 6, lane = tid & 63;
    const int r = (ct * 64) / OUT_;
    const int o0 = (ct * 64) % OUT_;
    const float* Bg = W + (size_t)r * (F_ + REL_) * OUT_ + o0;
    const int m0 = mt * 64;
    const int lm = lane & 15, q = lane >> 4;
    f32x4 acc[4] = {};
    for (int k0 = 0; k0 < F_; k0 += 32) {
        {
            int seg = (tid & 3) * 8, m = tid >> 2;
            const float* src = feat + (size_t)(m0 + m) * F_ + k0 + seg;
#pragma unroll
            for (int j = 0; j < 8; ++j) As[m][seg + j] = (_Float16)src[j];
        }
        {
            int kk = tid >> 3, ns = (tid & 7) * 8;
            const float* src = Bg + (size_t)(k0 + kk) * OUT_ + ns;
#pragma unroll
            for (int j = 0; j < 8; ++j) Bs[ns + j][kk] = (_Float16)src[j];
        }
        __syncthreads();
        f16x8 a = *(const f16x8*)&As[wave * 16 + lm][q * 8];
#pragma unroll
        for (int c4 = 0; c4 < 4; ++c4) {
            f16x8 b = *(const f16x8*)&Bs[c4 * 16 + lm][q * 8];
            acc[c4] = __builtin_amdgcn_mfma_f32_16x16x32_f16(a, b, acc[c4], 0, 0, 0);
        }
        __syncthreads();
    }
#pragma unroll
    for (int c4 = 0; c4 < 4; ++c4)
#pragma unroll
        for (int g = 0; g < 4; ++g) {
            int row = wave * 16 + (lane >> 4) * 4 + g;
            int col = c4 * 16 + lm;
            float v = acc[c4][g] + cb[r * OUT_ + o0 + col];
            HWb[((size_t)r * B_ * N_ + m0 + row) * OUT_ + o0 + col] = (_Float16)v;
        }
}

__global__ __launch_bounds__(256) void agg_kernel(const float* __restrict__ A1,
                                                  const float* __restrict__ A2,
                                                  const _Float16* __restrict__ HWb,
                                                  const float* __restrict__ bias,
                                                  float* __restrict__ out) {
    __shared__ _Float16 As[64][32];
    __shared__ _Float16 Bs[64][32];
    const int b = blockIdx.z, nt = blockIdx.y, ot = blockIdx.x;
    const int tid = threadIdx.x, wave = tid >> 6, lane = tid & 63;
    const int n0 = nt * 64, o0 = ot * 64;
    const int lm = lane & 15, q = lane >> 4;
    const size_t rstride = (size_t)B_ * N_ * OUT_;
    f32x4 mx[4];
#pragma unroll
    for (int i = 0; i < 4; ++i) mx[i] = f32x4{-1e30f, -1e30f, -1e30f, -1e30f};
#pragma unroll 1
    for (int rr = 0; rr < 4; ++rr) {
        const float* Ag = ((rr & 1) ? A2 : A1) + (size_t)b * N_ * N_;
        const bool tr = (rr >= 2);
        const int r = (rr < 2) ? rr : rr + 1;
        const _Float16* Bg = HWb + (size_t)r * rstride + (size_t)b * N_ * OUT_ + o0;
        f32x4 acc[4] = {};
        for (int k0 = 0; k0 < N_; k0 += 32) {
            if (!tr) {
                int seg = (tid & 3) * 8, m = tid >> 2;
                const float* src = Ag + (size_t)(n0 + m) * N_ + k0 + seg;
#pragma unroll
                for (int j = 0; j < 8; ++j) As[m][seg + j] = (_Float16)src[j];
            } else {
                int kk = tid >> 3, ms = (tid & 7) * 8;
                const float* src = Ag + (size_t)(k0 + kk) * N_ + n0 + ms;
#pragma unroll
                for (int j = 0; j < 8; ++j) As[ms + j][kk] = (_Float16)src[j];
            }
            {
                int kk = tid >> 3, ns = (tid & 7) * 8;
                const _Float16* src = Bg + (size_t)(k0 + kk) * OUT_ + ns;
#pragma unroll
                for (int j = 0; j < 8; ++j) Bs[ns + j][kk] = src[j];
            }
            __syncthreads();
            f16x8 a = *(const f16x8*)&As[wave * 16 + lm][q * 8];
#pragma unroll
            for (int c4 = 0; c4 < 4; ++c4) {
                f16x8 bb = *(const f16x8*)&Bs[c4 * 16 + lm][q * 8];
                acc[c4] = __builtin_amdgcn_mfma_f32_16x16x32_f16(a, bb, acc[c4], 0, 0, 0);
            }
            __syncthreads();
        }
#pragma unroll
        for (int c4 = 0; c4 < 4; ++c4)
#pragma unroll
            for (int g = 0; g < 4; ++g) mx[c4][g] = fmaxf(mx[c4][g], acc[c4][g]);
    }
#pragma unroll
    for (int c4 = 0; c4 < 4; ++c4)
#pragma unroll
        for (int g = 0; g < 4; ++g) {
            int row = wave * 16 + (lane >> 4) * 4 + g;
            int col = c4 * 16 + lm;
            size_t pos = ((size_t)b * N_ + n0 + row) * OUT_ + o0 + col;
            float v = mx[c4][g];
            v = fmaxf(v, (float)HWb[2 * rstride + pos]);
            v = fmaxf(v, (float)HWb[5 * rstride + pos]);
            v = fmaxf(v, (float)HWb[6 * rstride + pos]);
            out[pos] = v + bias[((size_t)(n0 + row)) * OUT_ + o0 + col];
        }
}

// ========================================================================================
extern "C" void kernel_launch(void* const* d_in, const int* in_sizes, int n_in,
                              void* d_out, int out_size, void* d_ws, size_t ws_size,
                              hipStream_t stream) {
    const float* feat = (const float*)d_in[0];
    const float* A1   = (const float*)d_in[1];
    const float* A2   = (const float*)d_in[2];
    const float* W    = (const float*)d_in[3];
    const float* We   = (const float*)d_in[4];
    const float* bias = (const float*)d_in[5];
    float* out = (float*)d_out;

    // fast-path ws layout (bytes) — AHW 2 K-halves (32 MB) + Af f16 copy (32 MB), ~97 MB
    const size_t OFF_CB   = 0;          //   8 KB
    const size_t OFF_WT   = 8192;       // 896 KB
    const size_t OFF_FE   = 1048576;    //   4 MB
    const size_t OFF_HWT  = 5242880;    //  16 MB
    const size_t OFF_HWN  = 22020096;   //  12 MB
    const size_t OFF_AHW  = 34603008;   //  32 MB (2 halves)
    const size_t OFF_AF   = 68157440;   //  32 MB (A1|A2 f16)
    const size_t WS_NEEDED = 101711872;

    if (ws_size >= WS_NEEDED) {
        float*    cbp = (float*)((char*)d_ws + OFF_CB);
        _Float16* WTp = (_Float16*)((char*)d_ws + OFF_WT);
        _Float16* Fe  = (_Float16*)((char*)d_ws + OFF_FE);
        _Float16* HWT = (_Float16*)((char*)d_ws + OFF_HWT);
        _Float16* HWN = (_Float16*)((char*)d_ws + OFF_HWN);
        _Float16* AHW = (_Float16*)((char*)d_ws + OFF_AHW);
        _Float16* Afp = (_Float16*)((char*)d_ws + OFF_AF);

        prep_kernel<<<2823, 256, 0, stream>>>(W, We, feat, cbp, WTp, Fe);
        hw7_kernel<<<9088, 256, 0, stream>>>(A1, A2, Fe, WTp, cbp, HWT, HWN, Afp);
        p2_kernel<<<1024, 256, 0, stream>>>(Afp, HWT, AHW);
        max_kernel<<<1024, 256, 0, stream>>>(AHW, HWN, bias, out);
    } else {
        // round-1 fallback
        float* cb = (float*)d_ws;
        _Float16* HWb = (_Float16*)((char*)d_ws + 8192);
        cbias_kernel<<<7, 256, 0, stream>>>(W, We, cb);
        hw_kernel<<<dim3(128, 28), 256, 0, stream>>>(feat, W, cb, HWb);
        agg_kernel<<<dim3(4, 16, 8), 256, 0, stream>>>(A1, A2, HWb, bias, out);
    }
}

// Round 10
// 173.413 us; speedup vs baseline: 1.0003x; 1.0003x over previous
//
#include <hip/hip_runtime.h>
#include <hip/hip_bf16.h>

#define B_ 8
#define N_ 1024
#define F_ 256
#define OUT_ 256
#define REL_ 16
#define NADJ_ 7

typedef __attribute__((ext_vector_type(8))) _Float16 f16x8;
typedef __attribute__((ext_vector_type(4))) _Float16 f16x4;
typedef __attribute__((ext_vector_type(4))) float f32x4;

__device__ __forceinline__ void gll16(const _Float16* g, _Float16* l) {
    __builtin_amdgcn_global_load_lds(
        (const __attribute__((address_space(1))) void*)g,
        (__attribute__((address_space(3))) void*)l, 16, 0, 0);
}

__device__ __forceinline__ f16x8 cvt8(float4 a, float4 b) {
    return f16x8{(_Float16)a.x, (_Float16)a.y, (_Float16)a.z, (_Float16)a.w,
                 (_Float16)b.x, (_Float16)b.y, (_Float16)b.z, (_Float16)b.w};
}

#define MEMPIN() asm volatile("" ::: "memory")

// perm order: rr 0..3 = r{0,1,3,4} (real adjacency), 4..6 = r{2,5,6} (identity adjacency)
__constant__ const int c_perm[7] = {0, 1, 3, 4, 2, 5, 6};

// ---------------- prep: cbias (blocks 0..6) | transW (7..1798) | cvt feat (1799..2822) ---
__global__ __launch_bounds__(256) void prep_kernel(const float* __restrict__ W,
                                                   const float* __restrict__ We,
                                                   const float* __restrict__ feat,
                                                   float* __restrict__ cb,
                                                   _Float16* __restrict__ WTp,
                                                   _Float16* __restrict__ Fe) {
    int bid = blockIdx.x, tid = threadIdx.x;
    if (bid < 7) {
        int idx = bid * 256 + tid;
        int j = idx / OUT_, o = idx % OUT_;
        int r = c_perm[j];
        const float* Wr = W + (size_t)r * (F_ + REL_) * OUT_;
        float s = 0.f;
#pragma unroll
        for (int d = 0; d < REL_; ++d) s += We[r * REL_ + d] * Wr[(F_ + d) * OUT_ + o];
        cb[idx] = s;
    } else if (bid < 1799) {
        int idx = (bid - 7) * 256 + tid;  // 7*65536 total
        int j = idx >> 16, rem = idx & 65535, o = rem >> 8, f = rem & 255;
        int r = c_perm[j];
        WTp[idx] = (_Float16)W[((size_t)r * (F_ + REL_) + f) * OUT_ + o];
    } else {
        int i = (bid - 1799) * 256 + tid;  // 262144 groups of 8
        size_t base = (size_t)i * 8;
        float4 a = *(const float4*)(feat + base);
        float4 b = *(const float4*)(feat + base + 4);
        *(f16x8*)(Fe + base) = cvt8(a, b);
    }
}

// ======= hw7: blocks [0,896): 7 HW GEMMs (3-stage gll16, verified r5-r9).
//         blocks [896,9088): A1/A2 -> f16 copy into Af (bandwidth-bound, overlaps GEMMs).
// z<4: HWT[z][b][o][m_local] = (Fe @ W[z])^T + cb ; z>=4: HWN[z-4][m][o] = Fe @ W[z] + cb.
__global__ __launch_bounds__(256) void hw7_kernel(const float* __restrict__ A1,
                                                  const float* __restrict__ A2,
                                                  const _Float16* __restrict__ Fe,
                                                  const _Float16* __restrict__ WTp,
                                                  const float* __restrict__ cb,
                                                  _Float16* __restrict__ HWT,
                                                  _Float16* __restrict__ HWN,
                                                  _Float16* __restrict__ Af) {
    __shared__ _Float16 S[3 * 8192];  // stage st: As = S+st*8192, Bs = As+4096 (BK=32)
    const int bid = blockIdx.x, tid = threadIdx.x;
    if (bid >= 896) {
        // A -> f16 cvt: 8192 blocks x 2048 elems = 16,777,216 = 2 x 8M
        size_t idx = ((size_t)(bid - 896) * 256 + tid) * 8;
        const float* src = (idx < 8388608) ? (A1 + idx) : (A2 + (idx - 8388608));
        float4 a = *(const float4*)(src);
        float4 b = *(const float4*)(src + 4);
        *(f16x8*)(Af + idx) = cvt8(a, b);
        return;
    }
    const int z = bid / 128, rem = bid % 128, bx = rem & 63, by = rem >> 6;
    const bool tr = (z < 4);
    const _Float16* A  = tr ? (WTp + (size_t)z * 65536) : Fe;
    const _Float16* Bt = tr ? Fe : (WTp + (size_t)z * 65536);
    const int m0 = (tr ? by : bx) * 128;
    const int n0 = (tr ? bx : by) * 128;
    const int wave = tid >> 6, lane = tid & 63, lm = lane & 15, q = lane >> 4;
    const int wr = (wave >> 1) * 64, wc = (wave & 1) * 64;
    const int srow = tid >> 2, sk = (tid & 3) * 8;
    const _Float16* ga0 = A + (size_t)(m0 + srow) * F_ + sk;
    const _Float16* ga1 = ga0 + (size_t)64 * F_;
    const _Float16* gb0 = Bt + (size_t)(n0 + srow) * F_ + sk;
    const _Float16* gb1 = gb0 + (size_t)64 * F_;

    f32x4 acc[4][4] = {};
    const int NT = 8;

    {
        gll16(ga0, S + tid * 8);
        gll16(ga1, S + 2048 + tid * 8);
        gll16(gb0, S + 4096 + tid * 8);
        gll16(gb1, S + 6144 + tid * 8);
        MEMPIN();
        gll16(ga0 + 32, S + 8192 + tid * 8);
        gll16(ga1 + 32, S + 8192 + 2048 + tid * 8);
        gll16(gb0 + 32, S + 8192 + 4096 + tid * 8);
        gll16(gb1 + 32, S + 8192 + 6144 + tid * 8);
        asm volatile("s_waitcnt vmcnt(4)" ::: "memory");  // stage-0 landed (mine)
        __builtin_amdgcn_s_barrier();
    }
    int cs = 0, ns = 1, fs = 2;
    for (int t = 0; t < NT; ++t) {
        if (t + 2 < NT) {
            const int k = (t + 2) * 32;
            _Float16* sb = S + fs * 8192;
            gll16(ga0 + k, sb + tid * 8);
            gll16(ga1 + k, sb + 2048 + tid * 8);
            gll16(gb0 + k, sb + 4096 + tid * 8);
            gll16(gb1 + k, sb + 6144 + tid * 8);
        }
        {
            const _Float16* Au = S + cs * 8192;
            const _Float16* Bu = Au + 4096;
            f16x8 af[4], bf[4];
#pragma unroll
            for (int i = 0; i < 4; ++i) af[i] = *(const f16x8*)(Au + (wr + i * 16 + lm) * 32 + q * 8);
#pragma unroll
            for (int j = 0; j < 4; ++j) bf[j] = *(const f16x8*)(Bu + (wc + j * 16 + lm) * 32 + q * 8);
            __builtin_amdgcn_s_setprio(1);
#pragma unroll
            for (int i = 0; i < 4; ++i)
#pragma unroll
                for (int j = 0; j < 4; ++j)
                    acc[i][j] = __builtin_amdgcn_mfma_f32_16x16x32_f16(af[i], bf[j], acc[i][j], 0, 0, 0);
            __builtin_amdgcn_s_setprio(0);
        }
        if (t + 1 < NT) {
            if (t + 2 < NT) asm volatile("s_waitcnt vmcnt(4)" ::: "memory");
            else            asm volatile("s_waitcnt vmcnt(0)" ::: "memory");
            __builtin_amdgcn_s_barrier();
        }
        int tmp = cs; cs = ns; ns = fs; fs = tmp;
    }
    const float* cbz = cb + (size_t)z * 256;
    if (tr) {
        // HWT[z][b][o][m_local]; tile lies in one b (n0 = bx*128)
        _Float16* C = HWT + (size_t)z * (8 * 256 * 1024) + (size_t)(n0 >> 10) * (256 * 1024);
        const int nl = n0 & 1023;
#pragma unroll
        for (int i = 0; i < 4; ++i)
#pragma unroll
            for (int j = 0; j < 4; ++j)
#pragma unroll
                for (int g = 0; g < 4; ++g) {
                    int row = wr + i * 16 + q * 4 + g;   // o
                    int col = wc + j * 16 + lm;          // m_local
                    float v = acc[i][j][g] + cbz[m0 + row];
                    C[(size_t)(m0 + row) * 1024 + nl + col] = (_Float16)v;
                }
    } else {
        _Float16* C = HWN + (size_t)(z - 4) * ((size_t)8192 * 256);
#pragma unroll
        for (int i = 0; i < 4; ++i)
#pragma unroll
            for (int j = 0; j < 4; ++j)
#pragma unroll
                for (int g = 0; g < 4; ++g) {
                    int row = wr + i * 16 + q * 4 + g;   // m
                    int col = wc + j * 16 + lm;          // o
                    float v = acc[i][j][g] + cbz[n0 + col];
                    C[(size_t)(m0 + row) * 256 + (n0 + col)] = (_Float16)v;
                }
    }
}

// ======= phase2: AHW[kh][rr][b][n][o] partial = A_rr[b][k-half] @ HWT[rr][b]-half^T ====
// f16 A everywhere. LDS 40 KB = A 2-stage (16 KB) + B 3-stage (24 KB) -> 4 blocks/CU:
// ALL 1024 blocks resident in one shift (16 waves/CU). rr<2: all-gll16 (A 2-stage,
// B 3-stage). rr>=2: reg-staged transpose scatter (regs are A's 3rd stage).
// Wait discipline (r5/r9-verified): wait OWN loads (counted) + lgkmcnt -> s_barrier.
// Mapping: b = d&7 (one b per XCD), slot = [kh | rr | member | mt].
__global__ __launch_bounds__(256) void p2_kernel(const _Float16* __restrict__ Af,
                                                 const _Float16* __restrict__ HWT,
                                                 _Float16* __restrict__ AHW) {
    __shared__ _Float16 As[2 * 4096];
    __shared__ _Float16 Bs[3 * 4096];
    const int d = blockIdx.x;
    const int b = d & 7, slot = d >> 3;
    const int kh = slot >> 6;                 // K half
    const int rr = (slot >> 4) & 3;           // relation
    const int member = (slot >> 3) & 1;       // o-tile
    const int mt = slot & 7;                  // m-tile

    const size_t slab = (size_t)B_ * N_ * OUT_;
    const _Float16* Ag = Af + (size_t)((rr & 1) * 8 + b) * 1048576;
    const _Float16* Bt = HWT + (size_t)(rr * 8 + b) * (256 * 1024);
    _Float16* C = AHW + (size_t)kh * (4 * slab) + (size_t)rr * slab + (size_t)b * (N_ * OUT_);
    const int m0 = mt * 128, n0 = member * 128, kbase = kh * 512;
    const int tid = threadIdx.x;
    const int wave = tid >> 6, lane = tid & 63, lm = lane & 15, q = lane >> 4;
    const int wr = (wave >> 1) * 64, wc = (wave & 1) * 64;
    const int srow = tid >> 2, sk = (tid & 3) * 8;
    const _Float16* gb0 = Bt + (size_t)(n0 + srow) * 1024 + kbase + sk;
    const _Float16* gb1 = gb0 + (size_t)64 * 1024;

    f32x4 acc[4][4] = {};
    const int NT = 16;

    auto STB = [&](int st, int k) {
        gll16(gb0 + k, Bs + st * 4096 + tid * 8);
        gll16(gb1 + k, Bs + st * 4096 + 2048 + tid * 8);
    };

    if (rr < 2) {
        // ---- straight: all-gll16. A 2-stage (stage = chunk&1), B 3-stage. ----
        const _Float16* ga0 = Ag + (size_t)(m0 + srow) * 1024 + kbase + sk;
        const _Float16* ga1 = ga0 + (size_t)64 * 1024;
        auto STA = [&](int st, int k) {
            gll16(ga0 + k, As + st * 4096 + tid * 8);
            gll16(ga1 + k, As + st * 4096 + 2048 + tid * 8);
        };
        // prologue: A0->st0, B0->st0, B1->st1; wait A0+B0 (leave B1 flying)
        STA(0, 0);
        STB(0, 0);
        MEMPIN();
        STB(1, 32);
        asm volatile("s_waitcnt vmcnt(2)" ::: "memory");
        __builtin_amdgcn_s_barrier();
        int bcs = 0, bns = 1, bfs = 2;
        for (int t = 0; t < NT; ++t) {
            const int acs = t & 1, ans = acs ^ 1;
            if (t + 1 < NT) STA(ans, (t + 1) * 32);     // A chunk t+1 (consumed next iter)
            if (t + 2 < NT) STB(bfs, (t + 2) * 32);     // B chunk t+2
            {
                const _Float16* Au = As + acs * 4096;
                const _Float16* Bu = Bs + bcs * 4096;
                f16x8 af[4], bf[4];
#pragma unroll
                for (int i = 0; i < 4; ++i) af[i] = *(const f16x8*)(Au + (wr + i * 16 + lm) * 32 + q * 8);
#pragma unroll
                for (int j = 0; j < 4; ++j) bf[j] = *(const f16x8*)(Bu + (wc + j * 16 + lm) * 32 + q * 8);
                __builtin_amdgcn_s_setprio(1);
#pragma unroll
                for (int i = 0; i < 4; ++i)
#pragma unroll
                    for (int j = 0; j < 4; ++j)
                        acc[i][j] = __builtin_amdgcn_mfma_f32_16x16x32_f16(af[i], bf[j], acc[i][j], 0, 0, 0);
                __builtin_amdgcn_s_setprio(0);
            }
            if (t + 1 < NT) {
                // prove A-ns (this iter) and B-ns (issued last iter) landed; B-fs keeps flying
                if (t + 2 < NT) asm volatile("s_waitcnt vmcnt(2)" ::: "memory");
                else            asm volatile("s_waitcnt vmcnt(0)" ::: "memory");
                __builtin_amdgcn_s_barrier();
            }
            int tmp = bcs; bcs = bns; bns = bfs; bfs = tmp;
        }
    } else {
        // ---- transposed: As[m][k] = Ag[kbase+t*32+kk][m0+m]; reg-staged scatter,
        //      A 2 LDS stages + 2 reg sets (the 3rd stage), B 3-stage gll16. ----
        const int kk4 = (tid >> 5) * 4;          // 0..28
        const int ms4 = (tid & 31) * 4;          // 0..124
        const int tsw = ((ms4 >> 4) & 3) << 3;
        const int wof = ms4 * 32 + (kk4 ^ tsw);
        const _Float16* gA0 = Ag + (size_t)(kbase + kk4) * 1024 + m0 + ms4;
        f16x4 R[2][4];
        auto RDT = [&](int s, int t) {
            const _Float16* p = gA0 + (size_t)t * 32 * 1024;
            R[s][0] = *(const f16x4*)(p);
            R[s][1] = *(const f16x4*)(p + 1024);
            R[s][2] = *(const f16x4*)(p + 2048);
            R[s][3] = *(const f16x4*)(p + 3072);
        };
        auto WRT = [&](int s, int st) {
            _Float16* wp = As + st * 4096 + wof;
#pragma unroll
            for (int c = 0; c < 4; ++c)
                *(f16x4*)(wp + c * 32) = f16x4{R[s][0][c], R[s][1][c], R[s][2][c], R[s][3][c]};
        };
        // prologue: chunk0 via regs->st0; B0->st0; chunk1 regs (set1); B1->st1
        RDT(0, 0);
        WRT(0, 0);
        MEMPIN();
        STB(0, 0);
        MEMPIN();
        RDT(1, 1);
        MEMPIN();
        STB(1, 32);
        asm volatile("s_waitcnt vmcnt(6)" ::: "memory");   // B0 landed (RDT0 consumed by WRT)
        asm volatile("s_waitcnt lgkmcnt(0)" ::: "memory");
        __builtin_amdgcn_s_barrier();
        int bcs = 0, bns = 1, bfs = 2;
        for (int t = 0; t < NT; ++t) {
            const int acs = t & 1, ans = acs ^ 1;
            if (t + 1 < NT) WRT(ans, ans);              // R[(t+1)&1] holds chunk t+1
            MEMPIN();
            if (t + 2 < NT) {
                RDT(acs, t + 2);                        // chunk t+2 -> set (t+2)&1 = t&1
                MEMPIN();
                STB(bfs, (t + 2) * 32);
            }
            {
                const _Float16* Au = As + acs * 4096;
                const _Float16* Bu = Bs + bcs * 4096;
                f16x8 af[4], bf[4];
#pragma unroll
                for (int i = 0; i < 4; ++i)
                    af[i] = *(const f16x8*)(Au + (wr + i * 16 + lm) * 32 + ((q ^ i) * 8));
#pragma unroll
                for (int j = 0; j < 4; ++j)
                    bf[j] = *(const f16x8*)(Bu + (wc + j * 16 + lm) * 32 + q * 8);
                __builtin_amdgcn_s_setprio(1);
#pragma unroll
                for (int i = 0; i < 4; ++i)
#pragma unroll
                    for (int j = 0; j < 4; ++j)
                        acc[i][j] = __builtin_amdgcn_mfma_f32_16x16x32_f16(af[i], bf[j], acc[i][j], 0, 0, 0);
                __builtin_amdgcn_s_setprio(0);
            }
            if (t + 1 < NT) {
                // outstanding: B-bns 2 (oldest, from t-1) + RDT 4 + B-bfs 2 (this iter)
                if (t + 2 < NT) asm volatile("s_waitcnt vmcnt(6)" ::: "memory");
                else            asm volatile("s_waitcnt vmcnt(0)" ::: "memory");
                asm volatile("s_waitcnt lgkmcnt(0)" ::: "memory");
                __builtin_amdgcn_s_barrier();
            }
            int tmp = bcs; bcs = bns; bns = bfs; bfs = tmp;
        }
    }
#pragma unroll
    for (int i = 0; i < 4; ++i)
#pragma unroll
        for (int j = 0; j < 4; ++j)
#pragma unroll
            for (int g = 0; g < 4; ++g) {
                int row = wr + i * 16 + q * 4 + g;
                int col = wc + j * 16 + lm;
                C[(size_t)(m0 + row) * 256 + (n0 + col)] = (_Float16)acc[i][j][g];
            }
}

// ======= final: out = max over rr of (AHW_half0 + AHW_half1), max with HWN, + bias =======
__global__ __launch_bounds__(256) void max_kernel(const _Float16* __restrict__ AHW,
                                                  const _Float16* __restrict__ HWN,
                                                  const float* __restrict__ bias,
                                                  float* __restrict__ out) {
    size_t i = ((size_t)blockIdx.x * 256 + threadIdx.x) * 8;
    const size_t slab = (size_t)B_ * N_ * OUT_;
    const size_t HS = 4 * slab;
    float m[8];
    {
        f16x8 v0 = *(const f16x8*)(AHW + i);
        f16x8 v1 = *(const f16x8*)(AHW + HS + i);
#pragma unroll
        for (int e = 0; e < 8; ++e) m[e] = (float)v0[e] + (float)v1[e];
    }
#pragma unroll
    for (int rr = 1; rr < 4; ++rr) {
        f16x8 v0 = *(const f16x8*)(AHW + rr * slab + i);
        f16x8 v1 = *(const f16x8*)(AHW + HS + rr * slab + i);
#pragma unroll
        for (int e = 0; e < 8; ++e) m[e] = fmaxf(m[e], (float)v0[e] + (float)v1[e]);
    }
#pragma unroll
    for (int j = 0; j < 3; ++j) {
        f16x8 w = *(const f16x8*)(HWN + j * slab + i);
#pragma unroll
        for (int e = 0; e < 8; ++e) m[e] = fmaxf(m[e], (float)w[e]);
    }
    size_t bidx = i & ((size_t)N_ * OUT_ - 1);
    float4 b0 = *(const float4*)(bias + bidx);
    float4 b1 = *(const float4*)(bias + bidx + 4);
    float4 o0 = {m[0] + b0.x, m[1] + b0.y, m[2] + b0.z, m[3] + b0.w};
    float4 o1 = {m[4] + b1.x, m[5] + b1.y, m[6] + b1.z, m[7] + b1.w};
    *(float4*)(out + i) = o0;
    *(float4*)(out + i + 4) = o1;
}

// ======================= round-1 fallback path (ws too small) ===========================
__global__ void cbias_kernel(const float* __restrict__ W, const float* __restrict__ We,
                             float* __restrict__ c) {
    int idx = blockIdx.x * 256 + threadIdx.x;
    if (idx >= NADJ_ * OUT_) return;
    int r = idx / OUT_, o = idx % OUT_;
    const float* Wr = W + (size_t)r * (F_ + REL_) * OUT_;
    float s = 0.f;
#pragma unroll
    for (int d = 0; d < REL_; ++d) s += We[r * REL_ + d] * Wr[(F_ + d) * OUT_ + o];
    c[idx] = s;
}

__global__ __launch_bounds__(256) void hw_kernel(const float* __restrict__ feat,
                                                 const float* __restrict__ W,
                                                 const float* __restrict__ cb,
                                                 _Float16* __restrict__ HWb) {
    __shared__ _Float16 As[64][32];
    __shared__ _Float16 Bs[64][32];
    const int mt = blockIdx.x, ct = blockIdx.y;
    const int tid = threadIdx.x, wave = tid >> 6, lane = tid & 63;
    const int r = (ct * 64) / OUT_;
    const int o0 = (ct * 64) % OUT_;
    const float* Bg = W + (size_t)r * (F_ + REL_) * OUT_ + o0;
    const int m0 = mt * 64;
    const int lm = lane & 15, q = lane >> 4;
    f32x4 acc[4] = {};
    for (int k0 = 0; k0 < F_; k0 += 32) {
        {
            int seg = (tid & 3) * 8, m = tid >> 2;
            const float* src = feat + (size_t)(m0 + m) * F_ + k0 + seg;
#pragma unroll
            for (int j = 0; j < 8; ++j) As[m][seg + j] = (_Float16)src[j];
        }
        {
            int kk = tid >> 3, ns = (tid & 7) * 8;
            const float* src = Bg + (size_t)(k0 + kk) * OUT_ + ns;
#pragma unroll
            for (int j = 0; j < 8; ++j) Bs[ns + j][kk] = (_Float16)src[j];
        }
        __syncthreads();
        f16x8 a = *(const f16x8*)&As[wave * 16 + lm][q * 8];
#pragma unroll
        for (int c4 = 0; c4 < 4; ++c4) {
            f16x8 b = *(const f16x8*)&Bs[c4 * 16 + lm][q * 8];
            acc[c4] = __builtin_amdgcn_mfma_f32_16x16x32_f16(a, b, acc[c4], 0, 0, 0);
        }
        __syncthreads();
    }
#pragma unroll
    for (int c4 = 0; c4 < 4; ++c4)
#pragma unroll
        for (int g = 0; g < 4; ++g) {
            int row = wave * 16 + (lane >> 4) * 4 + g;
            int col = c4 * 16 + lm;
            float v = acc[c4][g] + cb[r * OUT_ + o0 + col];
            HWb[((size_t)r * B_ * N_ + m0 + row) * OUT_ + o0 + col] = (_Float16)v;
        }
}

__global__ __launch_bounds__(256) void agg_kernel(const float* __restrict__ A1,
                                                  const float* __restrict__ A2,
                                                  const _Float16* __restrict__ HWb,
                                                  const float* __restrict__ bias,
                                                  float* __restrict__ out) {
    __shared__ _Float16 As[64][32];
    __shared__ _Float16 Bs[64][32];
    const int b = blockIdx.z, nt = blockIdx.y, ot = blockIdx.x;
    const int tid = threadIdx.x, wave = tid >> 6, lane = tid & 63;
    const int n0 = nt * 64, o0 = ot * 64;
    const int lm = lane & 15, q = lane >> 4;
    const size_t rstride = (size_t)B_ * N_ * OUT_;
    f32x4 mx[4];
#pragma unroll
    for (int i = 0; i < 4; ++i) mx[i] = f32x4{-1e30f, -1e30f, -1e30f, -1e30f};
#pragma unroll 1
    for (int rr = 0; rr < 4; ++rr) {
        const float* Ag = ((rr & 1) ? A2 : A1) + (size_t)b * N_ * N_;
        const bool tr = (rr >= 2);
        const int r = (rr < 2) ? rr : rr + 1;
        const _Float16* Bg = HWb + (size_t)r * rstride + (size_t)b * N_ * OUT_ + o0;
        f32x4 acc[4] = {};
        for (int k0 = 0; k0 < N_; k0 += 32) {
            if (!tr) {
                int seg = (tid & 3) * 8, m = tid >> 2;
                const float* src = Ag + (size_t)(n0 + m) * N_ + k0 + seg;
#pragma unroll
                for (int j = 0; j < 8; ++j) As[m][seg + j] = (_Float16)src[j];
            } else {
                int kk = tid >> 3, ms = (tid & 7) * 8;
                const float* src = Ag + (size_t)(k0 + kk) * N_ + n0 + ms;
#pragma unroll
                for (int j = 0; j < 8; ++j) As[ms + j][kk] = (_Float16)src[j];
            }
            {
                int kk = tid >> 3, ns = (tid & 7) * 8;
                const _Float16* src = Bg + (size_t)(k0 + kk) * OUT_ + ns;
#pragma unroll
                for (int j = 0; j < 8; ++j) Bs[ns + j][kk] = src[j];
            }
            __syncthreads();
            f16x8 a = *(const f16x8*)&As[wave * 16 + lm][q * 8];
#pragma unroll
            for (int c4 = 0; c4 < 4; ++c4) {
                f16x8 bb = *(const f16x8*)&Bs[c4 * 16 + lm][q * 8];
                acc[c4] = __builtin_amdgcn_mfma_f32_16x16x32_f16(a, bb, acc[c4], 0, 0, 0);
            }
            __syncthreads();
        }
#pragma unroll
        for (int c4 = 0; c4 < 4; ++c4)
#pragma unroll
            for (int g = 0; g < 4; ++g) mx[c4][g] = fmaxf(mx[c4][g], acc[c4][g]);
    }
#pragma unroll
    for (int c4 = 0; c4 < 4; ++c4)
#pragma unroll
        for (int g = 0; g < 4; ++g) {
            int row = wave * 16 + (lane >> 4) * 4 + g;
            int col = c4 * 16 + lm;
            size_t pos = ((size_t)b * N_ + n0 + row) * OUT_ + o0 + col;
            float v = mx[c4][g];
            v = fmaxf(v, (float)HWb[2 * rstride + pos]);
            v = fmaxf(v, (float)HWb[5 * rstride + pos]);
            v = fmaxf(v, (float)HWb[6 * rstride + pos]);
            out[pos] = v + bias[((size_t)(n0 + row)) * OUT_ + o0 + col];
        }
}

// ========================================================================================
extern "C" void kernel_launch(void* const* d_in, const int* in_sizes, int n_in,
                              void* d_out, int out_size, void* d_ws, size_t ws_size,
                              hipStream_t stream) {
    const float* feat = (const float*)d_in[0];
    const float* A1   = (const float*)d_in[1];
    const float* A2   = (const float*)d_in[2];
    const float* W    = (const float*)d_in[3];
    const float* We   = (const float*)d_in[4];
    const float* bias = (const float*)d_in[5];
    float* out = (float*)d_out;

    // fast-path ws layout (bytes) — AHW 2 K-halves (32 MB) + Af f16 copy (32 MB), ~97 MB
    const size_t OFF_CB   = 0;          //   8 KB
    const size_t OFF_WT   = 8192;       // 896 KB
    const size_t OFF_FE   = 1048576;    //   4 MB
    const size_t OFF_HWT  = 5242880;    //  16 MB
    const size_t OFF_HWN  = 22020096;   //  12 MB
    const size_t OFF_AHW  = 34603008;   //  32 MB (2 halves)
    const size_t OFF_AF   = 68157440;   //  32 MB (A1|A2 f16)
    const size_t WS_NEEDED = 101711872;

    if (ws_size >= WS_NEEDED) {
        float*    cbp = (float*)((char*)d_ws + OFF_CB);
        _Float16* WTp = (_Float16*)((char*)d_ws + OFF_WT);
        _Float16* Fe  = (_Float16*)((char*)d_ws + OFF_FE);
        _Float16* HWT = (_Float16*)((char*)d_ws + OFF_HWT);
        _Float16* HWN = (_Float16*)((char*)d_ws + OFF_HWN);
        _Float16* AHW = (_Float16*)((char*)d_ws + OFF_AHW);
        _Float16* Afp = (_Float16*)((char*)d_ws + OFF_AF);

        prep_kernel<<<2823, 256, 0, stream>>>(W, We, feat, cbp, WTp, Fe);
        hw7_kernel<<<9088, 256, 0, stream>>>(A1, A2, Fe, WTp, cbp, HWT, HWN, Afp);
        p2_kernel<<<1024, 256, 0, stream>>>(Afp, HWT, AHW);
        max_kernel<<<1024, 256, 0, stream>>>(AHW, HWN, bias, out);
    } else {
        // round-1 fallback
        float* cb = (float*)d_ws;
        _Float16* HWb = (_Float16*)((char*)d_ws + 8192);
        cbias_kernel<<<7, 256, 0, stream>>>(W, We, cb);
        hw_kernel<<<dim3(128, 28), 256, 0, stream>>>(feat, W, cb, HWb);
        agg_kernel<<<dim3(4, 16, 8), 256, 0, stream>>>(A1, A2, HWb, bias, out);
    }
}

// Round 11
// 169.808 us; speedup vs baseline: 1.0216x; 1.0212x over previous
//
#include <hip/hip_runtime.h>
#include <hip/hip_bf16.h>

#define B_ 8
#define N_ 1024
#define F_ 256
#define OUT_ 256
#define REL_ 16
#define NADJ_ 7

typedef __attribute__((ext_vector_type(8))) _Float16 f16x8;
typedef __attribute__((ext_vector_type(4))) _Float16 f16x4;
typedef __attribute__((ext_vector_type(4))) float f32x4;

__device__ __forceinline__ void gll16(const _Float16* g, _Float16* l) {
    __builtin_amdgcn_global_load_lds(
        (const __attribute__((address_space(1))) void*)g,
        (__attribute__((address_space(3))) void*)l, 16, 0, 0);
}

__device__ __forceinline__ f16x8 cvt8(float4 a, float4 b) {
    return f16x8{(_Float16)a.x, (_Float16)a.y, (_Float16)a.z, (_Float16)a.w,
                 (_Float16)b.x, (_Float16)b.y, (_Float16)b.z, (_Float16)b.w};
}

#define MEMPIN() asm volatile("" ::: "memory")

// perm order: rr 0..3 = r{0,1,3,4} (real adjacency), 4..6 = r{2,5,6} (identity adjacency)
__constant__ const int c_perm[7] = {0, 1, 3, 4, 2, 5, 6};

// ---- prep: cbias (0..6) | transW (7..1798) | cvt feat (1799..2822) | cvt A (2823..11014)
// A-cvt moved here from hw7: it has NO dependency on prep's other outputs (only p2 reads
// Af), and prep's dispatch is bandwidth-idle — while hw7's latency-bound GEMMs need the
// CUs to themselves.
__global__ __launch_bounds__(256) void prep_kernel(const float* __restrict__ W,
                                                   const float* __restrict__ We,
                                                   const float* __restrict__ feat,
                                                   const float* __restrict__ A1,
                                                   const float* __restrict__ A2,
                                                   float* __restrict__ cb,
                                                   _Float16* __restrict__ WTp,
                                                   _Float16* __restrict__ Fe,
                                                   _Float16* __restrict__ Af) {
    int bid = blockIdx.x, tid = threadIdx.x;
    if (bid < 7) {
        int idx = bid * 256 + tid;
        int j = idx / OUT_, o = idx % OUT_;
        int r = c_perm[j];
        const float* Wr = W + (size_t)r * (F_ + REL_) * OUT_;
        float s = 0.f;
#pragma unroll
        for (int d = 0; d < REL_; ++d) s += We[r * REL_ + d] * Wr[(F_ + d) * OUT_ + o];
        cb[idx] = s;
    } else if (bid < 1799) {
        int idx = (bid - 7) * 256 + tid;  // 7*65536 total
        int j = idx >> 16, rem = idx & 65535, o = rem >> 8, f = rem & 255;
        int r = c_perm[j];
        WTp[idx] = (_Float16)W[((size_t)r * (F_ + REL_) + f) * OUT_ + o];
    } else if (bid < 2823) {
        int i = (bid - 1799) * 256 + tid;  // 262144 groups of 8
        size_t base = (size_t)i * 8;
        float4 a = *(const float4*)(feat + base);
        float4 b = *(const float4*)(feat + base + 4);
        *(f16x8*)(Fe + base) = cvt8(a, b);
    } else {
        // A -> f16 cvt: 8192 blocks x 2048 elems = 16,777,216 = 2 x 8M
        size_t idx = ((size_t)(bid - 2823) * 256 + tid) * 8;
        const float* src = (idx < 8388608) ? (A1 + idx) : (A2 + (idx - 8388608));
        float4 a = *(const float4*)(src);
        float4 b = *(const float4*)(src + 4);
        *(f16x8*)(Af + idx) = cvt8(a, b);
    }
}

// ======= hw7: 7 HW GEMMs, 3-stage pipelined gll16 staging (verified r5-r10), grid 896.
// z<4: HWT[z][b][o][m_local] = (Fe @ W[z])^T + cb ; z>=4: HWN[z-4][m][o] = Fe @ W[z] + cb.
__global__ __launch_bounds__(256) void hw7_kernel(const _Float16* __restrict__ Fe,
                                                  const _Float16* __restrict__ WTp,
                                                  const float* __restrict__ cb,
                                                  _Float16* __restrict__ HWT,
                                                  _Float16* __restrict__ HWN) {
    __shared__ _Float16 S[3 * 8192];  // stage st: As = S+st*8192, Bs = As+4096 (BK=32)
    const int bid = blockIdx.x, tid = threadIdx.x;
    const int z = bid / 128, rem = bid % 128, bx = rem & 63, by = rem >> 6;
    const bool tr = (z < 4);
    const _Float16* A  = tr ? (WTp + (size_t)z * 65536) : Fe;
    const _Float16* Bt = tr ? Fe : (WTp + (size_t)z * 65536);
    const int m0 = (tr ? by : bx) * 128;
    const int n0 = (tr ? bx : by) * 128;
    const int wave = tid >> 6, lane = tid & 63, lm = lane & 15, q = lane >> 4;
    const int wr = (wave >> 1) * 64, wc = (wave & 1) * 64;
    const int srow = tid >> 2, sk = (tid & 3) * 8;
    const _Float16* ga0 = A + (size_t)(m0 + srow) * F_ + sk;
    const _Float16* ga1 = ga0 + (size_t)64 * F_;
    const _Float16* gb0 = Bt + (size_t)(n0 + srow) * F_ + sk;
    const _Float16* gb1 = gb0 + (size_t)64 * F_;

    f32x4 acc[4][4] = {};
    const int NT = 8;

    {
        gll16(ga0, S + tid * 8);
        gll16(ga1, S + 2048 + tid * 8);
        gll16(gb0, S + 4096 + tid * 8);
        gll16(gb1, S + 6144 + tid * 8);
        MEMPIN();
        gll16(ga0 + 32, S + 8192 + tid * 8);
        gll16(ga1 + 32, S + 8192 + 2048 + tid * 8);
        gll16(gb0 + 32, S + 8192 + 4096 + tid * 8);
        gll16(gb1 + 32, S + 8192 + 6144 + tid * 8);
        asm volatile("s_waitcnt vmcnt(4)" ::: "memory");  // stage-0 landed (mine)
        __builtin_amdgcn_s_barrier();
    }
    int cs = 0, ns = 1, fs = 2;
    for (int t = 0; t < NT; ++t) {
        if (t + 2 < NT) {
            const int k = (t + 2) * 32;
            _Float16* sb = S + fs * 8192;
            gll16(ga0 + k, sb + tid * 8);
            gll16(ga1 + k, sb + 2048 + tid * 8);
            gll16(gb0 + k, sb + 4096 + tid * 8);
            gll16(gb1 + k, sb + 6144 + tid * 8);
        }
        {
            const _Float16* Au = S + cs * 8192;
            const _Float16* Bu = Au + 4096;
            f16x8 af[4], bf[4];
#pragma unroll
            for (int i = 0; i < 4; ++i) af[i] = *(const f16x8*)(Au + (wr + i * 16 + lm) * 32 + q * 8);
#pragma unroll
            for (int j = 0; j < 4; ++j) bf[j] = *(const f16x8*)(Bu + (wc + j * 16 + lm) * 32 + q * 8);
            __builtin_amdgcn_s_setprio(1);
#pragma unroll
            for (int i = 0; i < 4; ++i)
#pragma unroll
                for (int j = 0; j < 4; ++j)
                    acc[i][j] = __builtin_amdgcn_mfma_f32_16x16x32_f16(af[i], bf[j], acc[i][j], 0, 0, 0);
            __builtin_amdgcn_s_setprio(0);
        }
        if (t + 1 < NT) {
            if (t + 2 < NT) asm volatile("s_waitcnt vmcnt(4)" ::: "memory");
            else            asm volatile("s_waitcnt vmcnt(0)" ::: "memory");
            __builtin_amdgcn_s_barrier();
        }
        int tmp = cs; cs = ns; ns = fs; fs = tmp;
    }
    const float* cbz = cb + (size_t)z * 256;
    if (tr) {
        // HWT[z][b][o][m_local]; tile lies in one b (n0 = bx*128)
        _Float16* C = HWT + (size_t)z * (8 * 256 * 1024) + (size_t)(n0 >> 10) * (256 * 1024);
        const int nl = n0 & 1023;
#pragma unroll
        for (int i = 0; i < 4; ++i)
#pragma unroll
            for (int j = 0; j < 4; ++j)
#pragma unroll
                for (int g = 0; g < 4; ++g) {
                    int row = wr + i * 16 + q * 4 + g;   // o
                    int col = wc + j * 16 + lm;          // m_local
                    float v = acc[i][j][g] + cbz[m0 + row];
                    C[(size_t)(m0 + row) * 1024 + nl + col] = (_Float16)v;
                }
    } else {
        _Float16* C = HWN + (size_t)(z - 4) * ((size_t)8192 * 256);
#pragma unroll
        for (int i = 0; i < 4; ++i)
#pragma unroll
            for (int j = 0; j < 4; ++j)
#pragma unroll
                for (int g = 0; g < 4; ++g) {
                    int row = wr + i * 16 + q * 4 + g;   // m
                    int col = wc + j * 16 + lm;          // o
                    float v = acc[i][j][g] + cbz[n0 + col];
                    C[(size_t)(m0 + row) * 256 + (n0 + col)] = (_Float16)v;
                }
    }
}

// ======= phase2: AHW[kh][rr][b][n][o] partial = A_rr[b][k-half] @ HWT[rr][b]-half^T ====
// f16 A everywhere. LDS 40 KB = A 2-stage (16 KB) + B 3-stage (24 KB) -> 4 blocks/CU:
// ALL 1024 blocks resident in one shift (16 waves/CU). rr<2: all-gll16 (A 2-stage,
// B 3-stage). rr>=2: reg-staged transpose scatter (regs are A's 3rd stage).
// Wait discipline (r5/r9-verified): wait OWN loads (counted) + lgkmcnt -> s_barrier.
// Mapping: b = d&7 (one b per XCD), slot = [kh | rr | member | mt].
__global__ __launch_bounds__(256) void p2_kernel(const _Float16* __restrict__ Af,
                                                 const _Float16* __restrict__ HWT,
                                                 _Float16* __restrict__ AHW) {
    __shared__ _Float16 As[2 * 4096];
    __shared__ _Float16 Bs[3 * 4096];
    const int d = blockIdx.x;
    const int b = d & 7, slot = d >> 3;
    const int kh = slot >> 6;                 // K half
    const int rr = (slot >> 4) & 3;           // relation
    const int member = (slot >> 3) & 1;       // o-tile
    const int mt = slot & 7;                  // m-tile

    const size_t slab = (size_t)B_ * N_ * OUT_;
    const _Float16* Ag = Af + (size_t)((rr & 1) * 8 + b) * 1048576;
    const _Float16* Bt = HWT + (size_t)(rr * 8 + b) * (256 * 1024);
    _Float16* C = AHW + (size_t)kh * (4 * slab) + (size_t)rr * slab + (size_t)b * (N_ * OUT_);
    const int m0 = mt * 128, n0 = member * 128, kbase = kh * 512;
    const int tid = threadIdx.x;
    const int wave = tid >> 6, lane = tid & 63, lm = lane & 15, q = lane >> 4;
    const int wr = (wave >> 1) * 64, wc = (wave & 1) * 64;
    const int srow = tid >> 2, sk = (tid & 3) * 8;
    const _Float16* gb0 = Bt + (size_t)(n0 + srow) * 1024 + kbase + sk;
    const _Float16* gb1 = gb0 + (size_t)64 * 1024;

    f32x4 acc[4][4] = {};
    const int NT = 16;

    auto STB = [&](int st, int k) {
        gll16(gb0 + k, Bs + st * 4096 + tid * 8);
        gll16(gb1 + k, Bs + st * 4096 + 2048 + tid * 8);
    };

    if (rr < 2) {
        // ---- straight: all-gll16. A 2-stage (stage = chunk&1), B 3-stage. ----
        const _Float16* ga0 = Ag + (size_t)(m0 + srow) * 1024 + kbase + sk;
        const _Float16* ga1 = ga0 + (size_t)64 * 1024;
        auto STA = [&](int st, int k) {
            gll16(ga0 + k, As + st * 4096 + tid * 8);
            gll16(ga1 + k, As + st * 4096 + 2048 + tid * 8);
        };
        // prologue: A0->st0, B0->st0, B1->st1; wait A0+B0 (leave B1 flying)
        STA(0, 0);
        STB(0, 0);
        MEMPIN();
        STB(1, 32);
        asm volatile("s_waitcnt vmcnt(2)" ::: "memory");
        __builtin_amdgcn_s_barrier();
        int bcs = 0, bns = 1, bfs = 2;
        for (int t = 0; t < NT; ++t) {
            const int acs = t & 1, ans = acs ^ 1;
            if (t + 1 < NT) STA(ans, (t + 1) * 32);     // A chunk t+1 (consumed next iter)
            if (t + 2 < NT) STB(bfs, (t + 2) * 32);     // B chunk t+2
            {
                const _Float16* Au = As + acs * 4096;
                const _Float16* Bu = Bs + bcs * 4096;
                f16x8 af[4], bf[4];
#pragma unroll
                for (int i = 0; i < 4; ++i) af[i] = *(const f16x8*)(Au + (wr + i * 16 + lm) * 32 + q * 8);
#pragma unroll
                for (int j = 0; j < 4; ++j) bf[j] = *(const f16x8*)(Bu + (wc + j * 16 + lm) * 32 + q * 8);
                __builtin_amdgcn_s_setprio(1);
#pragma unroll
                for (int i = 0; i < 4; ++i)
#pragma unroll
                    for (int j = 0; j < 4; ++j)
                        acc[i][j] = __builtin_amdgcn_mfma_f32_16x16x32_f16(af[i], bf[j], acc[i][j], 0, 0, 0);
                __builtin_amdgcn_s_setprio(0);
            }
            if (t + 1 < NT) {
                // prove A-ns (this iter) and B-ns (issued last iter) landed; B-fs keeps flying
                if (t + 2 < NT) asm volatile("s_waitcnt vmcnt(2)" ::: "memory");
                else            asm volatile("s_waitcnt vmcnt(0)" ::: "memory");
                __builtin_amdgcn_s_barrier();
            }
            int tmp = bcs; bcs = bns; bns = bfs; bfs = tmp;
        }
    } else {
        // ---- transposed: As[m][k] = Ag[kbase+t*32+kk][m0+m]; reg-staged scatter,
        //      A 2 LDS stages + 2 reg sets (the 3rd stage), B 3-stage gll16. ----
        const int kk4 = (tid >> 5) * 4;          // 0..28
        const int ms4 = (tid & 31) * 4;          // 0..124
        const int tsw = ((ms4 >> 4) & 3) << 3;
        const int wof = ms4 * 32 + (kk4 ^ tsw);
        const _Float16* gA0 = Ag + (size_t)(kbase + kk4) * 1024 + m0 + ms4;
        f16x4 R[2][4];
        auto RDT = [&](int s, int t) {
            const _Float16* p = gA0 + (size_t)t * 32 * 1024;
            R[s][0] = *(const f16x4*)(p);
            R[s][1] = *(const f16x4*)(p + 1024);
            R[s][2] = *(const f16x4*)(p + 2048);
            R[s][3] = *(const f16x4*)(p + 3072);
        };
        auto WRT = [&](int s, int st) {
            _Float16* wp = As + st * 4096 + wof;
#pragma unroll
            for (int c = 0; c < 4; ++c)
                *(f16x4*)(wp + c * 32) = f16x4{R[s][0][c], R[s][1][c], R[s][2][c], R[s][3][c]};
        };
        // prologue: chunk0 via regs->st0; B0->st0; chunk1 regs (set1); B1->st1
        RDT(0, 0);
        WRT(0, 0);
        MEMPIN();
        STB(0, 0);
        MEMPIN();
        RDT(1, 1);
        MEMPIN();
        STB(1, 32);
        asm volatile("s_waitcnt vmcnt(6)" ::: "memory");   // B0 landed (RDT0 consumed by WRT)
        asm volatile("s_waitcnt lgkmcnt(0)" ::: "memory");
        __builtin_amdgcn_s_barrier();
        int bcs = 0, bns = 1, bfs = 2;
        for (int t = 0; t < NT; ++t) {
            const int acs = t & 1, ans = acs ^ 1;
            if (t + 1 < NT) WRT(ans, ans);              // R[(t+1)&1] holds chunk t+1
            MEMPIN();
            if (t + 2 < NT) {
                RDT(acs, t + 2);                        // chunk t+2 -> set (t+2)&1 = t&1
                MEMPIN();
                STB(bfs, (t + 2) * 32);
            }
            {
                const _Float16* Au = As + acs * 4096;
                const _Float16* Bu = Bs + bcs * 4096;
                f16x8 af[4], bf[4];
#pragma unroll
                for (int i = 0; i < 4; ++i)
                    af[i] = *(const f16x8*)(Au + (wr + i * 16 + lm) * 32 + ((q ^ i) * 8));
#pragma unroll
                for (int j = 0; j < 4; ++j)
                    bf[j] = *(const f16x8*)(Bu + (wc + j * 16 + lm) * 32 + q * 8);
                __builtin_amdgcn_s_setprio(1);
#pragma unroll
                for (int i = 0; i < 4; ++i)
#pragma unroll
                    for (int j = 0; j < 4; ++j)
                        acc[i][j] = __builtin_amdgcn_mfma_f32_16x16x32_f16(af[i], bf[j], acc[i][j], 0, 0, 0);
                __builtin_amdgcn_s_setprio(0);
            }
            if (t + 1 < NT) {
                // outstanding: B-bns 2 (oldest, from t-1) + RDT 4 + B-bfs 2 (this iter)
                if (t + 2 < NT) asm volatile("s_waitcnt vmcnt(6)" ::: "memory");
                else            asm volatile("s_waitcnt vmcnt(0)" ::: "memory");
                asm volatile("s_waitcnt lgkmcnt(0)" ::: "memory");
                __builtin_amdgcn_s_barrier();
            }
            int tmp = bcs; bcs = bns; bns = bfs; bfs = tmp;
        }
    }
#pragma unroll
    for (int i = 0; i < 4; ++i)
#pragma unroll
        for (int j = 0; j < 4; ++j)
#pragma unroll
            for (int g = 0; g < 4; ++g) {
                int row = wr + i * 16 + q * 4 + g;
                int col = wc + j * 16 + lm;
                C[(size_t)(m0 + row) * 256 + (n0 + col)] = (_Float16)acc[i][j][g];
            }
}

// ======= final: out = max over rr of (AHW_half0 + AHW_half1), max with HWN, + bias =======
__global__ __launch_bounds__(256) void max_kernel(const _Float16* __restrict__ AHW,
                                                  const _Float16* __restrict__ HWN,
                                                  const float* __restrict__ bias,
                                                  float* __restrict__ out) {
    size_t i = ((size_t)blockIdx.x * 256 + threadIdx.x) * 8;
    const size_t slab = (size_t)B_ * N_ * OUT_;
    const size_t HS = 4 * slab;
    float m[8];
    {
        f16x8 v0 = *(const f16x8*)(AHW + i);
        f16x8 v1 = *(const f16x8*)(AHW + HS + i);
#pragma unroll
        for (int e = 0; e < 8; ++e) m[e] = (float)v0[e] + (float)v1[e];
    }
#pragma unroll
    for (int rr = 1; rr < 4; ++rr) {
        f16x8 v0 = *(const f16x8*)(AHW + rr * slab + i);
        f16x8 v1 = *(const f16x8*)(AHW + HS + rr * slab + i);
#pragma unroll
        for (int e = 0; e < 8; ++e) m[e] = fmaxf(m[e], (float)v0[e] + (float)v1[e]);
    }
#pragma unroll
    for (int j = 0; j < 3; ++j) {
        f16x8 w = *(const f16x8*)(HWN + j * slab + i);
#pragma unroll
        for (int e = 0; e < 8; ++e) m[e] = fmaxf(m[e], (float)w[e]);
    }
    size_t bidx = i & ((size_t)N_ * OUT_ - 1);
    float4 b0 = *(const float4*)(bias + bidx);
    float4 b1 = *(const float4*)(bias + bidx + 4);
    float4 o0 = {m[0] + b0.x, m[1] + b0.y, m[2] + b0.z, m[3] + b0.w};
    float4 o1 = {m[4] + b1.x, m[5] + b1.y, m[6] + b1.z, m[7] + b1.w};
    *(float4*)(out + i) = o0;
    *(float4*)(out + i + 4) = o1;
}

// ======================= round-1 fallback path (ws too small) ===========================
__global__ void cbias_kernel(const float* __restrict__ W, const float* __restrict__ We,
                             float* __restrict__ c) {
    int idx = blockIdx.x * 256 + threadIdx.x;
    if (idx >= NADJ_ * OUT_) return;
    int r = idx / OUT_, o = idx % OUT_;
    const float* Wr = W + (size_t)r * (F_ + REL_) * OUT_;
    float s = 0.f;
#pragma unroll
    for (int d = 0; d < REL_; ++d) s += We[r * REL_ + d] * Wr[(F_ + d) * OUT_ + o];
    c[idx] = s;
}

__global__ __launch_bounds__(256) void hw_kernel(const float* __restrict__ feat,
                                                 const float* __restrict__ W,
                                                 const float* __restrict__ cb,
                                                 _Float16* __restrict__ HWb) {
    __shared__ _Float16 As[64][32];
    __shared__ _Float16 Bs[64][32];
    const int mt = blockIdx.x, ct = blockIdx.y;
    const int tid = threadIdx.x, wave = tid >> 6, lane = tid & 63;
    const int r = (ct * 64) / OUT_;
    const int o0 = (ct * 64) % OUT_;
    const float* Bg = W + (size_t)r * (F_ + REL_) * OUT_ + o0;
    const int m0 = mt * 64;
    const int lm = lane & 15, q = lane >> 4;
    f32x4 acc[4] = {};
    for (int k0 = 0; k0 < F_; k0 += 32) {
        {
            int seg = (tid & 3) * 8, m = tid >> 2;
            const float* src = feat + (size_t)(m0 + m) * F_ + k0 + seg;
#pragma unroll
            for (int j = 0; j < 8; ++j) As[m][seg + j] = (_Float16)src[j];
        }
        {
            int kk = tid >> 3, ns = (tid & 7) * 8;
            const float* src = Bg + (size_t)(k0 + kk) * OUT_ + ns;
#pragma unroll
            for (int j = 0; j < 8; ++j) Bs[ns + j][kk] = (_Float16)src[j];
        }
        __syncthreads();
        f16x8 a = *(const f16x8*)&As[wave * 16 + lm][q * 8];
#pragma unroll
        for (int c4 = 0; c4 < 4; ++c4) {
            f16x8 b = *(const f16x8*)&Bs[c4 * 16 + lm][q * 8];
            acc[c4] = __builtin_amdgcn_mfma_f32_16x16x32_f16(a, b, acc[c4], 0, 0, 0);
        }
        __syncthreads();
    }
#pragma unroll
    for (int c4 = 0; c4 < 4; ++c4)
#pragma unroll
        for (int g = 0; g < 4; ++g) {
            int row = wave * 16 + (lane >> 4) * 4 + g;
            int col = c4 * 16 + lm;
            float v = acc[c4][g] + cb[r * OUT_ + o0 + col];
            HWb[((size_t)r * B_ * N_ + m0 + row) * OUT_ + o0 + col] = (_Float16)v;
        }
}

__global__ __launch_bounds__(256) void agg_kernel(const float* __restrict__ A1,
                                                  const float* __restrict__ A2,
                                                  const _Float16* __restrict__ HWb,
                                                  const float* __restrict__ bias,
                                                  float* __restrict__ out) {
    __shared__ _Float16 As[64][32];
    __shared__ _Float16 Bs[64][32];
    const int b = blockIdx.z, nt = blockIdx.y, ot = blockIdx.x;
    const int tid = threadIdx.x, wave = tid >> 6, lane = tid & 63;
    const int n0 = nt * 64, o0 = ot * 64;
    const int lm = lane & 15, q = lane >> 4;
    const size_t rstride = (size_t)B_ * N_ * OUT_;
    f32x4 mx[4];
#pragma unroll
    for (int i = 0; i < 4; ++i) mx[i] = f32x4{-1e30f, -1e30f, -1e30f, -1e30f};
#pragma unroll 1
    for (int rr = 0; rr < 4; ++rr) {
        const float* Ag = ((rr & 1) ? A2 : A1) + (size_t)b * N_ * N_;
        const bool tr = (rr >= 2);
        const int r = (rr < 2) ? rr : rr + 1;
        const _Float16* Bg = HWb + (size_t)r * rstride + (size_t)b * N_ * OUT_ + o0;
        f32x4 acc[4] = {};
        for (int k0 = 0; k0 < N_; k0 += 32) {
            if (!tr) {
                int seg = (tid & 3) * 8, m = tid >> 2;
                const float* src = Ag + (size_t)(n0 + m) * N_ + k0 + seg;
#pragma unroll
                for (int j = 0; j < 8; ++j) As[m][seg + j] = (_Float16)src[j];
            } else {
                int kk = tid >> 3, ms = (tid & 7) * 8;
                const float* src = Ag + (size_t)(k0 + kk) * N_ + n0 + ms;
#pragma unroll
                for (int j = 0; j < 8; ++j) As[ms + j][kk] = (_Float16)src[j];
            }
            {
                int kk = tid >> 3, ns = (tid & 7) * 8;
                const _Float16* src = Bg + (size_t)(k0 + kk) * OUT_ + ns;
#pragma unroll
                for (int j = 0; j < 8; ++j) Bs[ns + j][kk] = src[j];
            }
            __syncthreads();
            f16x8 a = *(const f16x8*)&As[wave * 16 + lm][q * 8];
#pragma unroll
            for (int c4 = 0; c4 < 4; ++c4) {
                f16x8 bb = *(const f16x8*)&Bs[c4 * 16 + lm][q * 8];
                acc[c4] = __builtin_amdgcn_mfma_f32_16x16x32_f16(a, bb, acc[c4], 0, 0, 0);
            }
            __syncthreads();
        }
#pragma unroll
        for (int c4 = 0; c4 < 4; ++c4)
#pragma unroll
            for (int g = 0; g < 4; ++g) mx[c4][g] = fmaxf(mx[c4][g], acc[c4][g]);
    }
#pragma unroll
    for (int c4 = 0; c4 < 4; ++c4)
#pragma unroll
        for (int g = 0; g < 4; ++g) {
            int row = wave * 16 + (lane >> 4) * 4 + g;
            int col = c4 * 16 + lm;
            size_t pos = ((size_t)b * N_ + n0 + row) * OUT_ + o0 + col;
            float v = mx[c4][g];
            v = fmaxf(v, (float)HWb[2 * rstride + pos]);
            v = fmaxf(v, (float)HWb[5 * rstride + pos]);
            v = fmaxf(v, (float)HWb[6 * rstride + pos]);
            out[pos] = v + bias[((size_t)(n0 + row)) * OUT_ + o0 + col];
        }
}

// ========================================================================================
extern "C" void kernel_launch(void* const* d_in, const int* in_sizes, int n_in,
                              void* d_out, int out_size, void* d_ws, size_t ws_size,
                              hipStream_t stream) {
    const float* feat = (const float*)d_in[0];
    const float* A1   = (const float*)d_in[1];
    const float* A2   = (const float*)d_in[2];
    const float* W    = (const float*)d_in[3];
    const float* We   = (const float*)d_in[4];
    const float* bias = (const float*)d_in[5];
    float* out = (float*)d_out;

    // fast-path ws layout (bytes) — AHW 2 K-halves (32 MB) + Af f16 copy (32 MB), ~97 MB
    const size_t OFF_CB   = 0;          //   8 KB
    const size_t OFF_WT   = 8192;       // 896 KB
    const size_t OFF_FE   = 1048576;    //   4 MB
    const size_t OFF_HWT  = 5242880;    //  16 MB
    const size_t OFF_HWN  = 22020096;   //  12 MB
    const size_t OFF_AHW  = 34603008;   //  32 MB (2 halves)
    const size_t OFF_AF   = 68157440;   //  32 MB (A1|A2 f16)
    const size_t WS_NEEDED = 101711872;

    if (ws_size >= WS_NEEDED) {
        float*    cbp = (float*)((char*)d_ws + OFF_CB);
        _Float16* WTp = (_Float16*)((char*)d_ws + OFF_WT);
        _Float16* Fe  = (_Float16*)((char*)d_ws + OFF_FE);
        _Float16* HWT = (_Float16*)((char*)d_ws + OFF_HWT);
        _Float16* HWN = (_Float16*)((char*)d_ws + OFF_HWN);
        _Float16* AHW = (_Float16*)((char*)d_ws + OFF_AHW);
        _Float16* Afp = (_Float16*)((char*)d_ws + OFF_AF);

        prep_kernel<<<11015, 256, 0, stream>>>(W, We, feat, A1, A2, cbp, WTp, Fe, Afp);
        hw7_kernel<<<896, 256, 0, stream>>>(Fe, WTp, cbp, HWT, HWN);
        p2_kernel<<<1024, 256, 0, stream>>>(Afp, HWT, AHW);
        max_kernel<<<1024, 256, 0, stream>>>(AHW, HWN, bias, out);
    } else {
        // round-1 fallback
        float* cb = (float*)d_ws;
        _Float16* HWb = (_Float16*)((char*)d_ws + 8192);
        cbias_kernel<<<7, 256, 0, stream>>>(W, We, cb);
        hw_kernel<<<dim3(128, 28), 256, 0, stream>>>(feat, W, cb, HWb);
        agg_kernel<<<dim3(4, 16, 8), 256, 0, stream>>>(A1, A2, HWb, bias, out);
    }
}